// Round 3
// baseline (1634.370 us; speedup 1.0000x reference)
//
#include <hip/hip_runtime.h>

#define BB 16384
#define DD 256
#define GPB 4   // groups per block (k2_fused)
#define TBG 8   // batches per group

typedef _Float16 f16;
typedef _Float16 h8 __attribute__((ext_vector_type(8)));
typedef float v4f __attribute__((ext_vector_type(4)));

#define MFMA(a,b,c) __builtin_amdgcn_mfma_f32_16x16x32_f16((a),(b),(c),0,0,0)

__device__ __forceinline__ float sigm(float x){ return 1.0f/(1.0f + __expf(-x)); }
__device__ __forceinline__ float tanh_f(float x){ float e = __expf(2.0f*x); return 1.0f - 2.0f/(e + 1.0f); }

// Swizzled LDS A-fragment read: 16B granule XOR'd with row&7 (bank-conflict-free ds_read_b128).
__device__ __forceinline__ h8 ldsA(const f16* s, int row, int stride, int k0){
  int g = (k0 >> 3) ^ (row & 7);
  return *reinterpret_cast<const h8*>(s + row*stride + g*8);
}

// LDS-only barrier: waits ds ops but NOT vmcnt -> prefetch global loads stay in flight.
__device__ __forceinline__ void bar_lds(){
  __builtin_amdgcn_sched_barrier(0);
  asm volatile("s_waitcnt lgkmcnt(0)" ::: "memory");
  __builtin_amdgcn_s_barrier();
  __builtin_amdgcn_sched_barrier(0);
}

// ---------------- k0a: f16 weight conversions ----------------
__global__ __launch_bounds__(512) void k0_convert(
    const float* __restrict__ Wih, const float* __restrict__ vW,
    const float* __restrict__ zW, const float* __restrict__ rW, const float* __restrict__ hW,
    f16* __restrict__ wih16, f16* __restrict__ wv16, f16* __restrict__ w2,
    f16* __restrict__ wzr1, f16* __restrict__ wh1)
{
  int idx = blockIdx.x*512 + threadIdx.x;
  if (idx < 393216){
    int j = idx >> 9, k = idx & 511;
    int sj = (j < 256) ? j : j + 256;  // packed rows: i(0..255), g(512..767), o(768..1023)
    wih16[idx] = (f16)Wih[sj*512 + k];
    return;
  }
  idx -= 393216;
  if (idx < 65536){ wv16[idx] = (f16)vW[idx]; return; }
  idx -= 65536;
  if (idx < 196608){
    int j = idx >> 8, k = idx & 255;
    float v = (j < 256) ? zW[j*512 + 256 + k]
            : (j < 512) ? rW[(j-256)*512 + 256 + k]
                        : hW[(j-512)*512 + 256 + k];
    w2[idx] = (f16)v;
    return;
  }
  idx -= 196608;
  if (idx < 131072){
    int j = idx >> 8, k = idx & 255;
    wzr1[idx] = (f16)((j < 256) ? zW[j*512 + k] : rW[(j-256)*512 + k]);
    return;
  }
  idx -= 131072;
  {
    int j = idx >> 8, k = idx & 255;
    wh1[idx] = (f16)hW[j*512 + k];
  }
}

// ---------------- k0b: Wqk'[d][e] = sum_j qW[j,e]*kW[j,d] ----------------
__global__ __launch_bounds__(256) void k0_wqkt(const float* __restrict__ qW, const float* __restrict__ kW,
                                               f16* __restrict__ wqkt)
{
  int d = blockIdx.x, e = threadIdx.x;
  float acc = 0.f;
  for (int j = 0; j < 256; ++j) acc += qW[j*256 + e] * kW[j*256 + d];
  wqkt[d*256 + e] = (f16)acc;
}

// ---------------- k0c: bqk[e]=qb@kW[:,e], u[e]=kb@qW[:,e], c0=qb.kb ----------------
__global__ __launch_bounds__(256) void k0_misc(const float* __restrict__ qW, const float* __restrict__ kW,
                                               const float* __restrict__ qb, const float* __restrict__ kb,
                                               float* __restrict__ bqk, float* __restrict__ u, float* __restrict__ c0)
{
  int e = threadIdx.x;
  float a = 0.f, b = 0.f;
  for (int j = 0; j < 256; ++j){ a += qb[j]*kW[j*256 + e]; b += kb[j]*qW[j*256 + e]; }
  bqk[e] = a; u[e] = b;
  if (e == 0){ float c = 0.f; for (int j = 0; j < 256; ++j) c += qb[j]*kb[j]; c0[0] = c; }
}

// ---------------- k1: frontend (norms -> W_t -> LSTM -> O' -> Qk, sQ) ----------------
__global__ __launch_bounds__(512) void k1_frontend(
    const float* __restrict__ O_t, const float* __restrict__ O_prev,
    const float* __restrict__ mlpW, const float* __restrict__ mlpB,
    const float* __restrict__ bih, const float* __restrict__ bhh,
    const f16* __restrict__ wih16, const f16* __restrict__ wqkt,
    const float* __restrict__ bqk, const float* __restrict__ u, const float* __restrict__ c0,
    float* __restrict__ wt_out, float* __restrict__ Qk, float* __restrict__ sQ)
{
  __shared__ f16 xs[32*512];
  __shared__ f16 o1[32*256];
  const int t   = threadIdx.x;
  const int b0  = blockIdx.x * 32;
  const int r   = t >> 4, sub = t & 15;
  const int b   = b0 + r;

  {
    float ot[16], op[16];
    float stt = 0.f, spp = 0.f, stp = 0.f;
    const float* pt = O_t    + b*DD + sub*16;
    const float* pp = O_prev + b*DD + sub*16;
#pragma unroll
    for (int i = 0; i < 4; ++i){
      float4 a = *reinterpret_cast<const float4*>(pt + i*4);
      float4 c = *reinterpret_cast<const float4*>(pp + i*4);
      ot[i*4+0]=a.x; ot[i*4+1]=a.y; ot[i*4+2]=a.z; ot[i*4+3]=a.w;
      op[i*4+0]=c.x; op[i*4+1]=c.y; op[i*4+2]=c.z; op[i*4+3]=c.w;
      stt += a.x*a.x + a.y*a.y + a.z*a.z + a.w*a.w;
      spp += c.x*c.x + c.y*c.y + c.z*c.z + c.w*c.w;
      stp += a.x*c.x + a.y*c.y + a.z*c.z + a.w*c.w;
    }
#pragma unroll
    for (int off = 8; off >= 1; off >>= 1){
      stt += __shfl_xor(stt, off);
      spp += __shfl_xor(spp, off);
      stp += __shfl_xor(stp, off);
    }
    float n_t = sqrtf(stt), n_p = sqrtf(spp);
    float r_d = sqrtf(fmaxf(stt - 2.f*stp + spp, 0.f));
    float r_a = stp / (n_t*n_p + 1e-6f);

    h8 h0, h1;
#pragma unroll
    for (int j = 0; j < 8; ++j){ h0[j] = (f16)op[j]; h1[j] = (f16)op[8+j]; }
    *reinterpret_cast<h8*>(&xs[r*512 + (((sub*2  ) ^ (r&7)))*8]) = h0;
    *reinterpret_cast<h8*>(&xs[r*512 + (((sub*2+1) ^ (r&7)))*8]) = h1;

    float wts[16];
#pragma unroll
    for (int i = 0; i < 16; ++i){
      int d = sub*16 + i;
      float xv = mlpW[d*3+0]*n_t + mlpW[d*3+1]*r_d + mlpW[d*3+2]*r_a + mlpB[d];
      wts[i] = 0.5f*(tanh_f(xv) + 1.0f);
    }
#pragma unroll
    for (int i = 0; i < 16; i += 4){
      float4 v; v.x=wts[i]; v.y=wts[i+1]; v.z=wts[i+2]; v.w=wts[i+3];
      *reinterpret_cast<float4*>(wt_out + (size_t)b*DD + sub*16 + i) = v;
    }
    h8 u0, u1;
#pragma unroll
    for (int j = 0; j < 8; ++j){ u0[j] = (f16)(ot[j]*wts[j]); u1[j] = (f16)(ot[8+j]*wts[8+j]); }
    *reinterpret_cast<h8*>(&xs[r*512 + (((32 + sub*2  ) ^ (r&7)))*8]) = u0;
    *reinterpret_cast<h8*>(&xs[r*512 + (((32 + sub*2+1) ^ (r&7)))*8]) = u1;
  }
  __syncthreads();

  const int w = t >> 6, l = t & 63;
  const int lr = l & 15, lk = l >> 4;

  {
    v4f acc[3][2][2];
#pragma unroll
    for (int g = 0; g < 3; ++g)
#pragma unroll
      for (int dt = 0; dt < 2; ++dt)
#pragma unroll
        for (int mt = 0; mt < 2; ++mt) acc[g][dt][mt] = (v4f){0.f,0.f,0.f,0.f};

#pragma unroll
    for (int ks = 0; ks < 16; ++ks){
      h8 A0 = ldsA(xs, lr,      512, ks*32 + lk*8);
      h8 A1 = ldsA(xs, 16 + lr, 512, ks*32 + lk*8);
#pragma unroll
      for (int dt = 0; dt < 2; ++dt){
        const int dbase = (w*2 + dt)*16;
#pragma unroll
        for (int g = 0; g < 3; ++g){
          const int jrow = g*256 + dbase + lr;
          h8 Bf = *reinterpret_cast<const h8*>(wih16 + jrow*512 + ks*32 + lk*8);
          acc[g][dt][0] = MFMA(A0, Bf, acc[g][dt][0]);
          acc[g][dt][1] = MFMA(A1, Bf, acc[g][dt][1]);
        }
      }
    }
#pragma unroll
    for (int dt = 0; dt < 2; ++dt){
      const int d  = (w*2 + dt)*16 + lr;
      const float bi = bih[d]       + bhh[d];
      const float bg = bih[512 + d] + bhh[512 + d];
      const float bo = bih[768 + d] + bhh[768 + d];
#pragma unroll
      for (int mt = 0; mt < 2; ++mt){
#pragma unroll
        for (int q = 0; q < 4; ++q){
          const int row = mt*16 + lk*4 + q;
          float iv = sigm(acc[0][dt][mt][q] + bi);
          float gv = tanh_f(acc[1][dt][mt][q] + bg);
          float ov = sigm(acc[2][dt][mt][q] + bo);
          float o  = ov * tanh_f(iv*gv);
          int g = ((d >> 3) ^ (row & 7));
          o1[row*256 + g*8 + (d & 7)] = (f16)o;
        }
      }
    }
  }
  __syncthreads();

  {
    float s = 0.f;
#pragma unroll
    for (int i = 0; i < 16; ++i){
      int dd = sub*16 + i;
      int g = ((dd >> 3) ^ (r & 7));
      s += (float)o1[r*256 + g*8 + (dd & 7)] * u[dd];
    }
#pragma unroll
    for (int off = 8; off >= 1; off >>= 1) s += __shfl_xor(s, off);
    if (sub == 0) sQ[b] = s + c0[0];
  }

  {
    v4f acc[2][2];
#pragma unroll
    for (int nt = 0; nt < 2; ++nt)
#pragma unroll
      for (int mt = 0; mt < 2; ++mt) acc[nt][mt] = (v4f){0.f,0.f,0.f,0.f};

#pragma unroll
    for (int ks = 0; ks < 8; ++ks){
      h8 A0 = ldsA(o1, lr,      256, ks*32 + lk*8);
      h8 A1 = ldsA(o1, 16 + lr, 256, ks*32 + lk*8);
#pragma unroll
      for (int nt = 0; nt < 2; ++nt){
        const int dcol = (w*2 + nt)*16 + lr;
        h8 Bf = *reinterpret_cast<const h8*>(wqkt + dcol*256 + ks*32 + lk*8);
        acc[nt][0] = MFMA(A0, Bf, acc[nt][0]);
        acc[nt][1] = MFMA(A1, Bf, acc[nt][1]);
      }
    }
#pragma unroll
    for (int nt = 0; nt < 2; ++nt){
      const int dcol = (w*2 + nt)*16 + lr;
      const float bq = bqk[dcol];
#pragma unroll
      for (int mt = 0; mt < 2; ++mt){
#pragma unroll
        for (int q = 0; q < 4; ++q){
          const int row = mt*16 + lk*4 + q;
          Qk[(size_t)(b0 + row)*DD + dcol] = acc[nt][mt][q] + bq;
        }
      }
    }
  }
}

// ---------------- k2_fused: attention + GRU memory update, mem read ONCE ----------------
// grid 512 x 512 threads; 4 groups of 8 batches per block; dyn LDS 152192 B.
// LDS map: msA[80*256]f16 @0 | msB @40960 | a2 @81920 (flush stg f32[32][256] aliases)
//          zrh f16[8*768] @122880 | oupf f32[8*256] @135168 | mbar f16[8*256] @143360
//          oup16 f16[8*256] @147456 | scores[80] @151552 | attn[80] @151872

__device__ __forceinline__ void issue_grp(float4* pf, const float* __restrict__ mem, int gb0, int t){
  const float* basep = mem + (size_t)gb0*10*DD;
  {
    const float* p = basep + (t>>4)*DD + (t&15)*16;
    pf[0] = reinterpret_cast<const float4*>(p)[0];
    pf[1] = reinterpret_cast<const float4*>(p)[1];
    pf[2] = reinterpret_cast<const float4*>(p)[2];
    pf[3] = reinterpret_cast<const float4*>(p)[3];
  }
  {
    const int s = t + 512;
    const float* p = basep + (s>>4)*DD + (s&15)*16;
    pf[4] = reinterpret_cast<const float4*>(p)[0];
    pf[5] = reinterpret_cast<const float4*>(p)[1];
    pf[6] = reinterpret_cast<const float4*>(p)[2];
    pf[7] = reinterpret_cast<const float4*>(p)[3];
  }
  if (t < 256){
    const int s = t + 1024;
    const float* p = basep + (s>>4)*DD + (s&15)*16;
    pf[8]  = reinterpret_cast<const float4*>(p)[0];
    pf[9]  = reinterpret_cast<const float4*>(p)[1];
    pf[10] = reinterpret_cast<const float4*>(p)[2];
    pf[11] = reinterpret_cast<const float4*>(p)[3];
  }
}

__device__ __forceinline__ void conv_slot(f16* __restrict__ buf, const float4* pf, int s,
    const float* __restrict__ Qk, int gb0, float* __restrict__ scoresL)
{
  const int rl = s >> 4, cs = s & 15;
  const float* qrow = Qk + (size_t)(gb0 + rl/10)*DD + cs*16;
  float sum = 0.f;
  h8 h0, h1;
  {
    float4 v = pf[0]; float4 q = reinterpret_cast<const float4*>(qrow)[0];
    sum += v.x*q.x + v.y*q.y + v.z*q.z + v.w*q.w;
    h0[0]=(f16)v.x; h0[1]=(f16)v.y; h0[2]=(f16)v.z; h0[3]=(f16)v.w;
  }
  {
    float4 v = pf[1]; float4 q = reinterpret_cast<const float4*>(qrow)[1];
    sum += v.x*q.x + v.y*q.y + v.z*q.z + v.w*q.w;
    h0[4]=(f16)v.x; h0[5]=(f16)v.y; h0[6]=(f16)v.z; h0[7]=(f16)v.w;
  }
  {
    float4 v = pf[2]; float4 q = reinterpret_cast<const float4*>(qrow)[2];
    sum += v.x*q.x + v.y*q.y + v.z*q.z + v.w*q.w;
    h1[0]=(f16)v.x; h1[1]=(f16)v.y; h1[2]=(f16)v.z; h1[3]=(f16)v.w;
  }
  {
    float4 v = pf[3]; float4 q = reinterpret_cast<const float4*>(qrow)[3];
    sum += v.x*q.x + v.y*q.y + v.z*q.z + v.w*q.w;
    h1[4]=(f16)v.x; h1[5]=(f16)v.y; h1[6]=(f16)v.z; h1[7]=(f16)v.w;
  }
  *reinterpret_cast<h8*>(buf + rl*256 + (((cs*2  ) ^ (rl&7)))*8) = h0;
  *reinterpret_cast<h8*>(buf + rl*256 + (((cs*2+1) ^ (rl&7)))*8) = h1;
#pragma unroll
  for (int off = 8; off >= 1; off >>= 1) sum += __shfl_xor(sum, off);
  if (cs == 0) scoresL[rl] = sum;
}

__global__ __launch_bounds__(512) void k2_fused(
    const float* __restrict__ mem, const float* __restrict__ Qk, const float* __restrict__ sQ,
    const f16* __restrict__ wv16, const float* __restrict__ v_b, const f16* __restrict__ w2,
    const f16* __restrict__ wzr1, const f16* __restrict__ wh1,
    const float* __restrict__ z_b, const float* __restrict__ r_b, const float* __restrict__ h_b,
    float* __restrict__ out, float* __restrict__ out1)
{
  extern __shared__ char smem[];
  f16*   msA     = (f16*)  (smem);
  f16*   msB     = (f16*)  (smem + 40960);
  f16*   a2      = (f16*)  (smem + 81920);
  float* stg     = (float*)(smem + 81920);
  f16*   zrh     = (f16*)  (smem + 122880);
  float* oupf    = (float*)(smem + 135168);
  f16*   mbar    = (f16*)  (smem + 143360);
  f16*   oup16   = (f16*)  (smem + 147456);
  float* scoresL = (float*)(smem + 151552);
  float* attnL   = (float*)(smem + 151872);

  const int t = threadIdx.x;
  const int w = t >> 6, l = t & 63, lr = l & 15, lk = l >> 4;
  const int blk_b0 = blockIdx.x * (GPB*TBG);

  float4 pf[12];
  issue_grp(pf, mem, blk_b0, t);

  for (int g = 0; g < GPB; ++g){
    const int gb0 = blk_b0 + g*TBG;
    f16* buf = (g & 1) ? msB : msA;

    // ---- convert prefetched fp32 -> f16 LDS tile + score partials ----
    conv_slot(buf, pf + 0, t,        Qk, gb0, scoresL);
    conv_slot(buf, pf + 4, t + 512,  Qk, gb0, scoresL);
    if (t < 256) conv_slot(buf, pf + 8, t + 1024, Qk, gb0, scoresL);
    bar_lds();

    // issue next group's mem loads; they stay in flight across LDS-only barriers
    if (g + 1 < GPB) issue_grp(pf, mem, blk_b0 + (g+1)*TBG, t);

    // ---- softmax over M=10 per batch ----
    if (t < TBG){
      const float sq = sQ[gb0 + t];
      float e[10]; float mx = -1e30f;
#pragma unroll
      for (int m = 0; m < 10; ++m){ e[m] = (scoresL[t*10 + m] + sq)*0.0625f; mx = fmaxf(mx, e[m]); }
      float ss = 0.f;
#pragma unroll
      for (int m = 0; m < 10; ++m){ e[m] = __expf(e[m] - mx); ss += e[m]; }
      float inv = 1.f/ss;
#pragma unroll
      for (int m = 0; m < 10; ++m) attnL[t*10 + m] = e[m]*inv;
    }
    bar_lds();

    // ---- mbar = sum_m attn*mem ----
    if (t < 256){
      const int rr = t >> 5, gg = t & 31;
      float a[8];
#pragma unroll
      for (int i = 0; i < 8; ++i) a[i] = 0.f;
#pragma unroll
      for (int m = 0; m < 10; ++m){
        const int row = rr*10 + m;
        const float wg = attnL[row];
        h8 h = *reinterpret_cast<const h8*>(buf + row*256 + ((gg ^ (row&7)))*8);
#pragma unroll
        for (int i = 0; i < 8; ++i) a[i] += wg*(float)h[i];
      }
      h8 hb;
#pragma unroll
      for (int i = 0; i < 8; ++i) hb[i] = (f16)a[i];
      *reinterpret_cast<h8*>(mbar + rr*256 + ((gg ^ (rr&7)))*8) = hb;
    }
    bar_lds();

    // ---- O_up = mbar @ vW^T + v_b ----
    {
      v4f accO[2]; accO[0] = (v4f){0.f,0.f,0.f,0.f}; accO[1] = (v4f){0.f,0.f,0.f,0.f};
#pragma unroll
      for (int ks = 0; ks < 8; ++ks){
        const int k0 = ks*32 + lk*8;
        h8 A = ldsA(mbar, lr, 256, k0);
#pragma unroll
        for (int nt = 0; nt < 2; ++nt){
          const int col = (w*2 + nt)*16 + lr;
          h8 Bf = *reinterpret_cast<const h8*>(wv16 + (size_t)col*256 + k0);
          accO[nt] = MFMA(A, Bf, accO[nt]);
        }
      }
#pragma unroll
      for (int nt = 0; nt < 2; ++nt){
        const int col = (w*2 + nt)*16 + lr;
        const float vb = v_b[col];
#pragma unroll
        for (int q = 0; q < 4; ++q){
          const int row = lk*4 + q;
          if (row < 8){
            float val = accO[nt][q] + vb;
            oupf[row*256 + col] = val;
            oup16[row*256 + ((col>>3) ^ (row&7))*8 + (col&7)] = (f16)val;
          }
        }
      }
    }
    bar_lds();

    // ---- coalesced O_up writes (out0, out2, memory_new[:,9,:]) ----
    {
      const int row = t >> 6, c4 = t & 63;
      float4 v = *reinterpret_cast<const float4*>(oupf + row*256 + c4*4);
      const size_t bb = (size_t)gb0 + row;
      *reinterpret_cast<float4*>(out + bb*DD + c4*4) = v;
      *reinterpret_cast<float4*>(out + (size_t)11*BB*DD + bb*DD + c4*4) = v;
      *reinterpret_cast<float4*>(out1 + (bb*10 + 9)*DD + c4*4) = v;
    }

    // ---- zrh = O_up @ [zW2;rW2;hW2]^T ----
    {
      v4f accZ[6];
#pragma unroll
      for (int j = 0; j < 6; ++j) accZ[j] = (v4f){0.f,0.f,0.f,0.f};
#pragma unroll
      for (int ks = 0; ks < 8; ++ks){
        const int k0 = ks*32 + lk*8;
        h8 A = ldsA(oup16, lr, 256, k0);
#pragma unroll
        for (int j = 0; j < 6; ++j){
          const int colg = (w*6 + j)*16 + lr;
          h8 Bf = *reinterpret_cast<const h8*>(w2 + (size_t)colg*256 + k0);
          accZ[j] = MFMA(A, Bf, accZ[j]);
        }
      }
#pragma unroll
      for (int j = 0; j < 6; ++j){
        const int colg = (w*6 + j)*16 + lr;
#pragma unroll
        for (int q = 0; q < 4; ++q){
          const int row = lk*4 + q;
          if (row < 8) zrh[row*768 + colg] = (f16)accZ[j][q];
        }
      }
    }
    bar_lds();

    float zreg[5][2][4];
    float zmv[5][2][4];

    // ---- z GEMM ----
    {
      v4f acc[5][2];
#pragma unroll
      for (int mt = 0; mt < 5; ++mt){ acc[mt][0]=(v4f){0.f,0.f,0.f,0.f}; acc[mt][1]=(v4f){0.f,0.f,0.f,0.f}; }
#pragma unroll
      for (int ks = 0; ks < 8; ++ks){
        const int k0 = ks*32 + lk*8;
        h8 A[5];
#pragma unroll
        for (int mt = 0; mt < 5; ++mt) A[mt] = ldsA(buf, mt*16 + lr, 256, k0);
#pragma unroll
        for (int nt = 0; nt < 2; ++nt){
          h8 Bf = *reinterpret_cast<const h8*>(wzr1 + (size_t)((w*2 + nt)*16 + lr)*256 + k0);
#pragma unroll
          for (int mt = 0; mt < 5; ++mt) acc[mt][nt] = MFMA(A[mt], Bf, acc[mt][nt]);
        }
      }
#pragma unroll
      for (int mt = 0; mt < 5; ++mt)
#pragma unroll
        for (int nt = 0; nt < 2; ++nt){
          const int col = (w*2 + nt)*16 + lr;
#pragma unroll
          for (int q = 0; q < 4; ++q){
            const int row = mt*16 + lk*4 + q;
            const int bl = row/10;
            float x = acc[mt][nt][q] + (float)zrh[bl*768 + col] + z_b[col];
            zreg[mt][nt][q] = sigm(x);
          }
        }
    }

    // ---- r GEMM -> a2 = r*mem (f16), zmv = z*mem (regs) ----
    {
      v4f acc[5][2];
#pragma unroll
      for (int mt = 0; mt < 5; ++mt){ acc[mt][0]=(v4f){0.f,0.f,0.f,0.f}; acc[mt][1]=(v4f){0.f,0.f,0.f,0.f}; }
#pragma unroll
      for (int ks = 0; ks < 8; ++ks){
        const int k0 = ks*32 + lk*8;
        h8 A[5];
#pragma unroll
        for (int mt = 0; mt < 5; ++mt) A[mt] = ldsA(buf, mt*16 + lr, 256, k0);
#pragma unroll
        for (int nt = 0; nt < 2; ++nt){
          h8 Bf = *reinterpret_cast<const h8*>(wzr1 + (size_t)(256 + (w*2 + nt)*16 + lr)*256 + k0);
#pragma unroll
          for (int mt = 0; mt < 5; ++mt) acc[mt][nt] = MFMA(A[mt], Bf, acc[mt][nt]);
        }
      }
#pragma unroll
      for (int mt = 0; mt < 5; ++mt)
#pragma unroll
        for (int nt = 0; nt < 2; ++nt){
          const int col = (w*2 + nt)*16 + lr;
#pragma unroll
          for (int q = 0; q < 4; ++q){
            const int row = mt*16 + lk*4 + q;
            const int bl = row/10;
            float x = acc[mt][nt][q] + (float)zrh[bl*768 + 256 + col] + r_b[col];
            float rv = sigm(x);
            float mvv = (float)buf[row*256 + ((col>>3) ^ (row&7))*8 + (col&7)];
            zmv[mt][nt][q] = zreg[mt][nt][q] * mvv;
            a2[row*256 + ((col>>3) ^ (row&7))*8 + (col&7)] = (f16)(rv*mvv);
          }
        }
    }
    bar_lds();

    // ---- h GEMM -> res = z*mem + (1-z)*tanh(...) ----
    {
      v4f acc[5][2];
#pragma unroll
      for (int mt = 0; mt < 5; ++mt){ acc[mt][0]=(v4f){0.f,0.f,0.f,0.f}; acc[mt][1]=(v4f){0.f,0.f,0.f,0.f}; }
#pragma unroll
      for (int ks = 0; ks < 8; ++ks){
        const int k0 = ks*32 + lk*8;
        h8 A[5];
#pragma unroll
        for (int mt = 0; mt < 5; ++mt) A[mt] = ldsA(a2, mt*16 + lr, 256, k0);
#pragma unroll
        for (int nt = 0; nt < 2; ++nt){
          h8 Bf = *reinterpret_cast<const h8*>(wh1 + (size_t)((w*2 + nt)*16 + lr)*256 + k0);
#pragma unroll
          for (int mt = 0; mt < 5; ++mt) acc[mt][nt] = MFMA(A[mt], Bf, acc[mt][nt]);
        }
      }
#pragma unroll
      for (int mt = 0; mt < 5; ++mt)
#pragma unroll
        for (int nt = 0; nt < 2; ++nt){
          const int col = (w*2 + nt)*16 + lr;
#pragma unroll
          for (int q = 0; q < 4; ++q){
            const int row = mt*16 + lk*4 + q;
            const int bl = row/10;
            float mtld = tanh_f(acc[mt][nt][q] + (float)zrh[bl*768 + 512 + col] + h_b[col]);
            zmv[mt][nt][q] = zmv[mt][nt][q] + (1.f - zreg[mt][nt][q])*mtld;  // final res
          }
        }
    }
    bar_lds();   // protect a2 (still being read as A) before stg overwrites it

    // ---- flush memory_new rows via LDS staging (coalesced float4 rows) ----
#pragma unroll
    for (int rd = 0; rd < 3; ++rd){
      const int rbase = rd*32;
#pragma unroll
      for (int mi = 0; mi < 2; ++mi){
        const int mt = rd*2 + mi;
        if (mt < 5){
#pragma unroll
          for (int nt = 0; nt < 2; ++nt){
            const int col = (w*2 + nt)*16 + lr;
#pragma unroll
            for (int q = 0; q < 4; ++q){
              const int row = mt*16 + lk*4 + q;
              stg[(row - rbase)*256 + col] = zmv[mt][nt][q];
            }
          }
        }
      }
      bar_lds();
      const int nf4 = (rd < 2) ? 2048 : 1024;
      for (int p = 0; p < 4; ++p){
        const int f = p*512 + t;
        if (f < nf4){
          const int rowl = f >> 6;
          const int grow = rbase + rowl;
          const int bl = grow/10;
          const int m  = grow - bl*10;
          if (m){
            float4 v = *reinterpret_cast<const float4*>(stg + (size_t)f*4);
            *reinterpret_cast<float4*>(out1 + ((size_t)(gb0 + bl)*10 + (m-1))*DD + (f & 63)*4) = v;
          }
        }
      }
      bar_lds();
    }
  }
}

extern "C" void kernel_launch(void* const* d_in, const int* in_sizes, int n_in,
                              void* d_out, int out_size, void* d_ws, size_t ws_size,
                              hipStream_t stream)
{
  (void)in_sizes; (void)n_in; (void)out_size; (void)ws_size;

  const float* O_t    = (const float*)d_in[0];
  const float* O_prev = (const float*)d_in[1];
  const float* mem    = (const float*)d_in[2];
  const float* mlpW   = (const float*)d_in[3];
  const float* mlpB   = (const float*)d_in[4];
  const float* Wih    = (const float*)d_in[5];
  // d_in[6] lstm_Whh unused (h0 = 0)
  const float* bih    = (const float*)d_in[7];
  const float* bhh    = (const float*)d_in[8];
  const float* qW     = (const float*)d_in[9];
  const float* qb     = (const float*)d_in[10];
  const float* kW     = (const float*)d_in[11];
  const float* kb     = (const float*)d_in[12];
  const float* vW     = (const float*)d_in[13];
  const float* vb     = (const float*)d_in[14];
  const float* zW     = (const float*)d_in[15];
  const float* zb     = (const float*)d_in[16];
  const float* rW     = (const float*)d_in[17];
  const float* rb     = (const float*)d_in[18];
  const float* hW     = (const float*)d_in[19];
  const float* hb     = (const float*)d_in[20];

  char* ws = (char*)d_ws;
  f16*   wih16 = (f16*)  (ws + 0);
  f16*   wqkt  = (f16*)  (ws + 786432);
  f16*   wv16  = (f16*)  (ws + 917504);
  f16*   w2    = (f16*)  (ws + 1048576);
  f16*   wzr1  = (f16*)  (ws + 1441792);
  f16*   wh1   = (f16*)  (ws + 1703936);
  float* bqk   = (float*)(ws + 1835008);
  float* u     = (float*)(ws + 1836032);
  float* c0    = (float*)(ws + 1837056);
  float* Qk    = (float*)(ws + 2097152);
  float* sQ    = (float*)(ws + 18874368);

  float* out    = (float*)d_out;
  float* wt_out = out + (size_t)12*BB*DD;
  float* out1   = out + (size_t)BB*DD;

  hipFuncSetAttribute((const void*)k2_fused, hipFuncAttributeMaxDynamicSharedMemorySize, 152192);

  k0_convert<<<dim3(1664), dim3(512), 0, stream>>>(Wih, vW, zW, rW, hW, wih16, wv16, w2, wzr1, wh1);
  k0_wqkt  <<<dim3(256),  dim3(256), 0, stream>>>(qW, kW, wqkt);
  k0_misc  <<<dim3(1),    dim3(256), 0, stream>>>(qW, kW, qb, kb, bqk, u, c0);
  k1_frontend<<<dim3(512), dim3(512), 0, stream>>>(O_t, O_prev, mlpW, mlpB, bih, bhh,
                                                   wih16, wqkt, bqk, u, c0, wt_out, Qk, sQ);
  k2_fused <<<dim3(512), dim3(512), 152192, stream>>>(mem, Qk, sQ, wv16, vb, w2, wzr1, wh1,
                                                      zb, rb, hb, out, out1);
}